// Round 6
// baseline (211.599 us; speedup 1.0000x reference)
//
#include <hip/hip_runtime.h>
#include <math.h>

#define BB 8
#define SS 128
#define NN 129
#define DD 256
#define HH 8
#define LN_EPS 1e-5f

// ws layout (float offsets)
#define OFF_A    0        // a:     [B][S][D]
#define OFF_BPT  262144   // bp_t:  [B][D][S]  (b_ + b_e1, transposed)
#define OFF_CPT  524288   // cp_t:  [B][D][S]  (a + b_ + b_e1, transposed)
#define OFF_VART 786432   // var_t: [B][D][S]  (nv[:,1:,:] transposed)
#define OFF_V    1048576  // v:     [B][N][D]
#define OFF_SQ   1312768  // sq:    [B][H][N]
#define OFF_SK   1321024  // sk:    [B][H][N]
#define OFF_MA   1329280
#define OFF_QA   1330304
#define OFF_MB   1331328
#define OFF_QB   1332352
#define OFF_MC   1333376
#define OFF_QC   1334400
#define OFF_U    1335424  // U: [D][H]
#define OFF_UB   1337472  // ubias: [H]
#define OFF_G    1337600  // G:  [B][S][S]
#define OFF_VV   1468672  // VV: [B][S][S]   (end 1599744 floats = 6.4 MB)

// ============ KA3: projections (M=8 tiles) + stats + transposes + U-fold ====
// Weight traffic halved vs R5 (M=4): each block reads full weight cols once
// and amortizes over 8 rows.
__global__ __launch_bounds__(256) void ka3(
    const float* __restrict__ desc, const float* __restrict__ nv,
    const float* __restrict__ W_gt, const float* __restrict__ b_gt,
    const float* __restrict__ W_e1, const float* __restrict__ b_e1,
    const float* __restrict__ W_q, const float* __restrict__ b_q,
    const float* __restrict__ W_k, const float* __restrict__ b_k,
    const float* __restrict__ W_v, const float* __restrict__ b_v,
    const float* __restrict__ W_e2, const float* __restrict__ b_e2,
    const float* __restrict__ w_attn,
    float* __restrict__ a, float* __restrict__ bp_t, float* __restrict__ cp_t,
    float* __restrict__ var_t, float* __restrict__ v,
    float* __restrict__ sq, float* __restrict__ sk,
    float* __restrict__ ma, float* __restrict__ qa, float* __restrict__ mb,
    float* __restrict__ qb, float* __restrict__ mc, float* __restrict__ qc,
    float* __restrict__ U, float* __restrict__ ubias) {
    const int bx = blockIdx.x, t = threadIdx.x;
    __shared__ __attribute__((aligned(16))) float rowbuf[DD][8];
    __shared__ __attribute__((aligned(16))) float drow[DD][8];
    __shared__ float part[48][4];

    if (bx < 128) {
        // ---- part A: d = desc@W_gt+b_gt ; a = d@We1_t ; bp = d@We1_b+be1 ---
        const int b = bx >> 4, s0 = (bx & 15) * 8;
        for (int e = t; e < 8 * DD; e += 256) {
            int r = e >> 8, k = e & 255;
            rowbuf[k][r] = desc[(size_t)(b * SS + s0 + r) * DD + k];
        }
        __syncthreads();
        const int c = t;
        {
            float dv[8] = {0.f, 0.f, 0.f, 0.f, 0.f, 0.f, 0.f, 0.f};
#pragma unroll 8
            for (int k = 0; k < DD; k++) {
                float w = W_gt[k * DD + c];
                float4 d0 = *(const float4*)&rowbuf[k][0];
                float4 d1 = *(const float4*)&rowbuf[k][4];
                dv[0] = fmaf(d0.x, w, dv[0]); dv[1] = fmaf(d0.y, w, dv[1]);
                dv[2] = fmaf(d0.z, w, dv[2]); dv[3] = fmaf(d0.w, w, dv[3]);
                dv[4] = fmaf(d1.x, w, dv[4]); dv[5] = fmaf(d1.y, w, dv[5]);
                dv[6] = fmaf(d1.z, w, dv[6]); dv[7] = fmaf(d1.w, w, dv[7]);
            }
            float bg = b_gt[c];
            float4 s0v, s1v;
            s0v.x = dv[0] + bg; s0v.y = dv[1] + bg; s0v.z = dv[2] + bg; s0v.w = dv[3] + bg;
            s1v.x = dv[4] + bg; s1v.y = dv[5] + bg; s1v.z = dv[6] + bg; s1v.w = dv[7] + bg;
            *(float4*)&drow[c][0] = s0v;
            *(float4*)&drow[c][4] = s1v;
        }
        __syncthreads();
        float av[8] = {0.f, 0.f, 0.f, 0.f, 0.f, 0.f, 0.f, 0.f};
        float bv[8] = {0.f, 0.f, 0.f, 0.f, 0.f, 0.f, 0.f, 0.f};
#pragma unroll 4
        for (int k = 0; k < DD; k++) {
            float wa = W_e1[k * DD + c];
            float wb = W_e1[(DD + k) * DD + c];
            float4 d0 = *(const float4*)&drow[k][0];
            float4 d1 = *(const float4*)&drow[k][4];
            av[0] = fmaf(d0.x, wa, av[0]); av[1] = fmaf(d0.y, wa, av[1]);
            av[2] = fmaf(d0.z, wa, av[2]); av[3] = fmaf(d0.w, wa, av[3]);
            av[4] = fmaf(d1.x, wa, av[4]); av[5] = fmaf(d1.y, wa, av[5]);
            av[6] = fmaf(d1.z, wa, av[6]); av[7] = fmaf(d1.w, wa, av[7]);
            bv[0] = fmaf(d0.x, wb, bv[0]); bv[1] = fmaf(d0.y, wb, bv[1]);
            bv[2] = fmaf(d0.z, wb, bv[2]); bv[3] = fmaf(d0.w, wb, bv[3]);
            bv[4] = fmaf(d1.x, wb, bv[4]); bv[5] = fmaf(d1.y, wb, bv[5]);
            bv[6] = fmaf(d1.z, wb, bv[6]); bv[7] = fmaf(d1.w, wb, bv[7]);
        }
        float be1 = b_e1[c];
        float cv[8];
#pragma unroll
        for (int r = 0; r < 8; r++) { bv[r] += be1; cv[r] = av[r] + bv[r]; }
#pragma unroll
        for (int r = 0; r < 8; r++) a[(size_t)(b * SS + s0 + r) * DD + c] = av[r];
        float4 f4;
        f4.x = bv[0]; f4.y = bv[1]; f4.z = bv[2]; f4.w = bv[3];
        *(float4*)(bp_t + (size_t)(b * DD + c) * SS + s0) = f4;
        f4.x = bv[4]; f4.y = bv[5]; f4.z = bv[6]; f4.w = bv[7];
        *(float4*)(bp_t + (size_t)(b * DD + c) * SS + s0 + 4) = f4;
        f4.x = cv[0]; f4.y = cv[1]; f4.z = cv[2]; f4.w = cv[3];
        *(float4*)(cp_t + (size_t)(b * DD + c) * SS + s0) = f4;
        f4.x = cv[4]; f4.y = cv[5]; f4.z = cv[6]; f4.w = cv[7];
        *(float4*)(cp_t + (size_t)(b * DD + c) * SS + s0 + 4) = f4;
        float nvv[8];
#pragma unroll
        for (int r = 0; r < 8; r++) nvv[r] = nv[(size_t)(b * NN + 1 + s0 + r) * DD + c];
        f4.x = nvv[0]; f4.y = nvv[1]; f4.z = nvv[2]; f4.w = nvv[3];
        *(float4*)(var_t + (size_t)(b * DD + c) * SS + s0) = f4;
        f4.x = nvv[4]; f4.y = nvv[5]; f4.z = nvv[6]; f4.w = nvv[7];
        *(float4*)(var_t + (size_t)(b * DD + c) * SS + s0 + 4) = f4;
        // 48 block reductions: 8 rows x {sumA,sumA2,sumB,sumB2,sumC,sumC2}
        float vals[48];
#pragma unroll
        for (int r = 0; r < 8; r++) {
            vals[r * 6 + 0] = av[r]; vals[r * 6 + 1] = av[r] * av[r];
            vals[r * 6 + 2] = bv[r]; vals[r * 6 + 3] = bv[r] * bv[r];
            vals[r * 6 + 4] = cv[r]; vals[r * 6 + 5] = cv[r] * cv[r];
        }
        int lane = t & 63, wid = t >> 6;
#pragma unroll
        for (int vv = 0; vv < 48; vv++) {
            float x = vals[vv];
            for (int o = 32; o; o >>= 1) x += __shfl_xor(x, o, 64);
            if (lane == 0) part[vv][wid] = x;
        }
        __syncthreads();
        if (t < 48) {
            float ssum = (part[t][0] + part[t][1]) + (part[t][2] + part[t][3]);
            int st = t % 6;
            int row = b * SS + s0 + t / 6;
            float m = ssum * (1.f / DD);
            float* dstp = (st == 0) ? ma : (st == 1) ? qa : (st == 2) ? mb
                         : (st == 3) ? qb : (st == 4) ? mc : qc;
            dstp[row] = m;
        }
    } else if (bx < 264) {
        // ---- part B: q/k/v projections (M=8) + collapsed sq/sk -------------
        const int idx = bx - 128;           // 0..135 = 8 b x 17 tiles
        const int b = idx / 17, n0 = (idx % 17) * 8;
        for (int e = t; e < 8 * DD; e += 256) {
            int r = e >> 8, k = e & 255;
            int n = n0 + r; if (n >= NN) n = NN - 1;
            rowbuf[k][r] = nv[(size_t)(b * NN + n) * DD + k];
        }
        __syncthreads();
        const int c = t;
        float qv[8] = {0.f, 0.f, 0.f, 0.f, 0.f, 0.f, 0.f, 0.f};
        float kv[8] = {0.f, 0.f, 0.f, 0.f, 0.f, 0.f, 0.f, 0.f};
        float vv[8] = {0.f, 0.f, 0.f, 0.f, 0.f, 0.f, 0.f, 0.f};
#pragma unroll 4
        for (int k = 0; k < DD; k++) {
            float wq = W_q[k * DD + c], wk = W_k[k * DD + c], wvv = W_v[k * DD + c];
            float4 r0 = *(const float4*)&rowbuf[k][0];
            float4 r1 = *(const float4*)&rowbuf[k][4];
            qv[0] = fmaf(r0.x, wq, qv[0]); qv[1] = fmaf(r0.y, wq, qv[1]);
            qv[2] = fmaf(r0.z, wq, qv[2]); qv[3] = fmaf(r0.w, wq, qv[3]);
            qv[4] = fmaf(r1.x, wq, qv[4]); qv[5] = fmaf(r1.y, wq, qv[5]);
            qv[6] = fmaf(r1.z, wq, qv[6]); qv[7] = fmaf(r1.w, wq, qv[7]);
            kv[0] = fmaf(r0.x, wk, kv[0]); kv[1] = fmaf(r0.y, wk, kv[1]);
            kv[2] = fmaf(r0.z, wk, kv[2]); kv[3] = fmaf(r0.w, wk, kv[3]);
            kv[4] = fmaf(r1.x, wk, kv[4]); kv[5] = fmaf(r1.y, wk, kv[5]);
            kv[6] = fmaf(r1.z, wk, kv[6]); kv[7] = fmaf(r1.w, wk, kv[7]);
            vv[0] = fmaf(r0.x, wvv, vv[0]); vv[1] = fmaf(r0.y, wvv, vv[1]);
            vv[2] = fmaf(r0.z, wvv, vv[2]); vv[3] = fmaf(r0.w, wvv, vv[3]);
            vv[4] = fmaf(r1.x, wvv, vv[4]); vv[5] = fmaf(r1.y, wvv, vv[5]);
            vv[6] = fmaf(r1.z, wvv, vv[6]); vv[7] = fmaf(r1.w, wvv, vv[7]);
        }
        float bq = b_q[c], bk = b_k[c], bvb = b_v[c];
        float waq = w_attn[c & 31];
        float wak = w_attn[32 + (c & 31)];
        int h = c >> 5;
#pragma unroll
        for (int r = 0; r < 8; r++) {
            int n = n0 + r;
            if (n < NN) v[(size_t)(b * NN + n) * DD + c] = vv[r] + bvb;
            float xq = (qv[r] + bq) * waq, xk = (kv[r] + bk) * wak;
#pragma unroll
            for (int o = 16; o; o >>= 1) { xq += __shfl_xor(xq, o); xk += __shfl_xor(xk, o); }
            if ((c & 31) == 0 && n < NN) {
                sq[(size_t)(b * HH + h) * NN + n] = xq;
                sk[(size_t)(b * HH + h) * NN + n] = xk;
            }
        }
    } else {
        // ---- part C: fold W_e2/we -> U, b_e2/we -> ubias -------------------
        const int ri = bx - 264;  // 0..63
        const int c = t;
        const float wec = w_attn[64 + (c & 31)];
#pragma unroll
        for (int rr = 0; rr < 4; rr++) {
            int r = ri * 4 + rr;
            float x = W_e2[(size_t)r * DD + c] * wec;
#pragma unroll
            for (int o = 16; o; o >>= 1) x += __shfl_xor(x, o);
            if ((c & 31) == 0) U[r * HH + (c >> 5)] = x;
        }
        if (ri == 0) {
            float x = b_e2[c] * wec;
#pragma unroll
            for (int o = 16; o; o >>= 1) x += __shfl_xor(x, o);
            if ((c & 31) == 0) ubias[c >> 5] = x;
        }
    }
}

// ============ KGRAM: G = a@bp^T and VV = var@var^T, 16x64 tiles =============
// C[i][j] = sum_d Arow[i][d] * Bt[d][j]. 256 blocks (128 G + 128 VV).
__global__ __launch_bounds__(256) void kgram(
    const float* __restrict__ a, const float* __restrict__ bp_t,
    const float* __restrict__ nv, const float* __restrict__ var_t,
    float* __restrict__ G, float* __restrict__ VV) {
    const int bx = blockIdx.x, t = threadIdx.x;
    const bool isG = bx < 128;
    const int idx = isG ? bx : bx - 128;
    const int b = idx >> 4, tl = idx & 15;
    const int i0 = (tl >> 1) * 16, j0 = (tl & 1) * 64;
    const float* Asrc = isG ? (a + ((size_t)b * SS + i0) * DD)
                            : (nv + ((size_t)b * NN + 1 + i0) * DD);
    const float* Bt = (isG ? bp_t : var_t) + (size_t)b * DD * SS;
    float* C = (isG ? G : VV) + (size_t)b * SS * SS;
    __shared__ __attribute__((aligned(16))) float Al[16][DD];  // 16 KB
    for (int e = t; e < 16 * DD / 4; e += 256) {
        int r = e >> 6, c4 = e & 63;
        *(float4*)&Al[r][c4 * 4] = *(const float4*)&Asrc[(size_t)r * DD + c4 * 4];
    }
    __syncthreads();
    const int dg = t & 3, jl = t >> 2;  // 4 d-groups x 64 j
    float acc[16] = {0.f, 0.f, 0.f, 0.f, 0.f, 0.f, 0.f, 0.f,
                     0.f, 0.f, 0.f, 0.f, 0.f, 0.f, 0.f, 0.f};
    const float* bp = Bt + (size_t)(dg * 64) * SS + j0 + jl;
#pragma unroll 4
    for (int dd = 0; dd < 64; dd++) {
        float bvv = bp[(size_t)dd * SS];
        int d = dg * 64 + dd;
#pragma unroll
        for (int i = 0; i < 16; i++) acc[i] = fmaf(Al[i][d], bvv, acc[i]);
    }
#pragma unroll
    for (int i = 0; i < 16; i++) {
        acc[i] += __shfl_xor(acc[i], 1);
        acc[i] += __shfl_xor(acc[i], 2);
    }
    if (dg == 0) {
#pragma unroll
        for (int i = 0; i < 16; i++) C[(size_t)(i0 + i) * SS + j0 + jl] = acc[i];
    }
}

// ============ KB3: closed-form LN + relu + U-dot + scores + softmax =========
// 2-i register tiles; pass1 replaced by G/VV lookups; wave-uniform d-groups
// (all LDS operand reads are broadcasts; B loads fully coalesced 512B float2).
__global__ __launch_bounds__(256) void kb3(
    const float* __restrict__ a, const float* __restrict__ bp_t, const float* __restrict__ cp_t,
    const float* __restrict__ ma, const float* __restrict__ qa,
    const float* __restrict__ mb, const float* __restrict__ qb,
    const float* __restrict__ mc, const float* __restrict__ qc,
    const float* __restrict__ G, const float* __restrict__ VV,
    const float* __restrict__ sq, const float* __restrict__ sk,
    const float* __restrict__ ln_g, const float* __restrict__ ln_b,
    const float* __restrict__ U, const float* __restrict__ ubias,
    const float* __restrict__ b_attn,
    float* __restrict__ attn) {
    const int it = blockIdx.x, b = blockIdx.y;
    const int i0 = it * 2;
    const int t = threadIdx.x;
    const int dg = t >> 6, jl = t & 63;  // wave-uniform d-group, lane = j-pair
    __shared__ float Arow[2][DD];
    __shared__ __attribute__((aligned(8))) float2 lnsm[DD];
    __shared__ __attribute__((aligned(16))) float4 Usm[DD][2];
    __shared__ __attribute__((aligned(8))) float rsm[2][SS], nmm[2][SS], mkm[2][SS], pnm[2][SS];
    __shared__ float skm[HH * NN];
    __shared__ float sqb[2][HH], ubm[HH];
    __shared__ float sc[2][HH][NN + 3];
    __shared__ __attribute__((aligned(8))) float red[4][2][HH][SS];  // 32 KB

    {
        int ic0 = i0, ic1 = (i0 + 1 < NN) ? i0 + 1 : NN - 1;
        Arow[0][t] = (ic0 >= 1) ? a[((size_t)b * SS + ic0 - 1) * DD + t] : 0.f;
        Arow[1][t] = (ic1 >= 1) ? a[((size_t)b * SS + ic1 - 1) * DD + t] : 0.f;
        float2 g; g.x = ln_g[t]; g.y = ln_b[t]; lnsm[t] = g;
        Usm[t][0] = *(const float4*)&U[t * HH];
        Usm[t][1] = *(const float4*)&U[t * HH + 4];
        for (int e = t; e < HH * NN; e += 256) skm[e] = sk[(size_t)b * HH * NN + e];
        if (t < 16) {
            int il = t >> 3, h = t & 7;
            int i = i0 + il; if (i > NN - 1) i = NN - 1;
            sqb[il][h] = sq[(size_t)b * HH * NN + h * NN + i] + b_attn[0];
        }
        if (t < HH) ubm[t] = ubias[t];
    }
    __syncthreads();
    // per-(i,j) LN stats from precomputed row-stats + G cross-term; mask from VV
    if (t < SS) {
        const int j = t;
#pragma unroll
        for (int il = 0; il < 2; il++) {
            int i = i0 + il; if (i > NN - 1) i = NN - 1;
            float rs, nm, mk, pen;
            if (i == 0) {
                float mu = mc[b * SS + j], q2 = qc[b * SS + j];
                rs = rsqrtf(q2 - mu * mu + LN_EPS); nm = -mu * rs; mk = 1.f; pen = 0.f;
            } else {
                float cr = G[((size_t)b * SS + i - 1) * SS + j];
                float dv = VV[((size_t)b * SS + i - 1) * SS + j];
                float muA = ma[b * SS + i - 1], qA = qa[b * SS + i - 1];
                float muB = mb[b * SS + j], qB = qb[b * SS + j];
                float mu = muA + muB;
                float var = qA + qB + 2.f * cr * (1.f / DD) - mu * mu;
                rs = rsqrtf(var + LN_EPS); nm = -mu * rs;
                mk = ((i - 1) != j && dv > 0.f) ? 1.f : 0.f;
                pen = (mk == 0.f) ? -1e9f : 0.f;
            }
            rsm[il][j] = rs; nmm[il][j] = nm; mkm[il][j] = mk; pnm[il][j] = pen;
        }
    }
    __syncthreads();
    // main elementwise pass: 64 d-iters, 2 j x 2 i x (LN+relu+8h U-dot)
    float acc[2][HH][2];
#pragma unroll
    for (int il = 0; il < 2; il++)
#pragma unroll
        for (int h = 0; h < HH; h++) { acc[il][h][0] = 0.f; acc[il][h][1] = 0.f; }
    {
        const float* B0 = ((i0 == 0) ? cp_t : bp_t) + ((size_t)b * DD + dg * 64) * SS + 2 * jl;
        const float* B1 = bp_t + ((size_t)b * DD + dg * 64) * SS + 2 * jl;
        float2 r0 = *(const float2*)&rsm[0][2 * jl];
        float2 n0 = *(const float2*)&nmm[0][2 * jl];
        float2 r1 = *(const float2*)&rsm[1][2 * jl];
        float2 n1 = *(const float2*)&nmm[1][2 * jl];
#pragma unroll 4
        for (int dd = 0; dd < 64; dd++) {
            const int d = dg * 64 + dd;
            float2 bA = *(const float2*)(B0 + (size_t)dd * SS);
            float2 bB = *(const float2*)(B1 + (size_t)dd * SS);
            float A0 = Arow[0][d], A1 = Arow[1][d];
            float2 gb = lnsm[d];
            float4 u0 = Usm[d][0], u1 = Usm[d][1];
            // il = 0
            {
                float y0 = fmaf(A0 + bA.x, r0.x, n0.x); y0 = fmaf(y0, gb.x, gb.y);
                float y1 = fmaf(A0 + bA.y, r0.y, n0.y); y1 = fmaf(y1, gb.x, gb.y);
                float e0 = fmaxf(y0, 0.f), e1 = fmaxf(y1, 0.f);
                acc[0][0][0] = fmaf(e0, u0.x, acc[0][0][0]); acc[0][0][1] = fmaf(e1, u0.x, acc[0][0][1]);
                acc[0][1][0] = fmaf(e0, u0.y, acc[0][1][0]); acc[0][1][1] = fmaf(e1, u0.y, acc[0][1][1]);
                acc[0][2][0] = fmaf(e0, u0.z, acc[0][2][0]); acc[0][2][1] = fmaf(e1, u0.z, acc[0][2][1]);
                acc[0][3][0] = fmaf(e0, u0.w, acc[0][3][0]); acc[0][3][1] = fmaf(e1, u0.w, acc[0][3][1]);
                acc[0][4][0] = fmaf(e0, u1.x, acc[0][4][0]); acc[0][4][1] = fmaf(e1, u1.x, acc[0][4][1]);
                acc[0][5][0] = fmaf(e0, u1.y, acc[0][5][0]); acc[0][5][1] = fmaf(e1, u1.y, acc[0][5][1]);
                acc[0][6][0] = fmaf(e0, u1.z, acc[0][6][0]); acc[0][6][1] = fmaf(e1, u1.z, acc[0][6][1]);
                acc[0][7][0] = fmaf(e0, u1.w, acc[0][7][0]); acc[0][7][1] = fmaf(e1, u1.w, acc[0][7][1]);
            }
            // il = 1
            {
                float y0 = fmaf(A1 + bB.x, r1.x, n1.x); y0 = fmaf(y0, gb.x, gb.y);
                float y1 = fmaf(A1 + bB.y, r1.y, n1.y); y1 = fmaf(y1, gb.x, gb.y);
                float e0 = fmaxf(y0, 0.f), e1 = fmaxf(y1, 0.f);
                acc[1][0][0] = fmaf(e0, u0.x, acc[1][0][0]); acc[1][0][1] = fmaf(e1, u0.x, acc[1][0][1]);
                acc[1][1][0] = fmaf(e0, u0.y, acc[1][1][0]); acc[1][1][1] = fmaf(e1, u0.y, acc[1][1][1]);
                acc[1][2][0] = fmaf(e0, u0.z, acc[1][2][0]); acc[1][2][1] = fmaf(e1, u0.z, acc[1][2][1]);
                acc[1][3][0] = fmaf(e0, u0.w, acc[1][3][0]); acc[1][3][1] = fmaf(e1, u0.w, acc[1][3][1]);
                acc[1][4][0] = fmaf(e0, u1.x, acc[1][4][0]); acc[1][4][1] = fmaf(e1, u1.x, acc[1][4][1]);
                acc[1][5][0] = fmaf(e0, u1.y, acc[1][5][0]); acc[1][5][1] = fmaf(e1, u1.y, acc[1][5][1]);
                acc[1][6][0] = fmaf(e0, u1.z, acc[1][6][0]); acc[1][6][1] = fmaf(e1, u1.z, acc[1][6][1]);
                acc[1][7][0] = fmaf(e0, u1.w, acc[1][7][0]); acc[1][7][1] = fmaf(e1, u1.w, acc[1][7][1]);
            }
        }
    }
#pragma unroll
    for (int il = 0; il < 2; il++)
#pragma unroll
        for (int h = 0; h < HH; h++) {
            float2 w; w.x = acc[il][h][0]; w.y = acc[il][h][1];
            *(float2*)&red[dg][il][h][2 * jl] = w;
        }
    __syncthreads();
    // reduce 4 d-groups + assemble scores
    for (int e = t; e < 2 * HH * SS; e += 256) {
        int il = e >> 10, h = (e >> 7) & 7, j = e & 127;
        float s = (red[0][il][h][j] + red[1][il][h][j]) + (red[2][il][h][j] + red[3][il][h][j]);
        sc[il][h][1 + j] = sqb[il][h] + skm[h * NN + 1 + j] + (s + ubm[h]) * mkm[il][j] + pnm[il][j];
    }
    if (t < 16) { int il = t >> 3, h = t & 7; sc[il][h][0] = sqb[il][h] + skm[h * NN] - 1e9f; }
    __syncthreads();
    // softmax: 16 rows (2 i x 8 h) x 16 lanes
    {
        const int row = t >> 4, l = t & 15;
        const int il = row >> 3, h = row & 7;
        const int i = i0 + il;
        float m = -INFINITY;
        for (int j = l; j < NN; j += 16) m = fmaxf(m, sc[il][h][j]);
#pragma unroll
        for (int o = 8; o; o >>= 1) m = fmaxf(m, __shfl_xor(m, o, 16));
        float s = 0.f;
        for (int j = l; j < NN; j += 16) { float e = __expf(sc[il][h][j] - m); sc[il][h][j] = e; s += e; }
#pragma unroll
        for (int o = 8; o; o >>= 1) s += __shfl_xor(s, o, 16);
        float inv = 1.f / s;
        if (i < NN) {
            float* arow = attn + (((size_t)b * HH + h) * NN + i) * NN;
            for (int j = l; j < NN; j += 16) arow[j] = sc[il][h][j] * inv;
        }
    }
}

// ============ KC3: ctx = attn@v ; out = ctx@W_o + b_o (4-i tiles) ===========
__global__ __launch_bounds__(256) void kc3(
    const float* __restrict__ attn, const float* __restrict__ v,
    const float* __restrict__ W_o, const float* __restrict__ b_o,
    float* __restrict__ out) {
    const int b = blockIdx.y, i0 = blockIdx.x * 4;
    const int t = threadIdx.x;
    __shared__ float ar[4][HH * 132];
    __shared__ float csmT[4][DD];
    for (int e = t; e < 4 * HH * NN; e += 256) {
        int il = e / (HH * NN), rem = e - il * (HH * NN);
        int h = rem / NN, j = rem - h * NN;
        int i = i0 + il; if (i >= NN) i = NN - 1;
        ar[il][h * 132 + j] = attn[(((size_t)b * HH + h) * NN + i) * NN + j];
    }
    __syncthreads();
    {
        const int d = t, h = d >> 5;
        float c0 = 0.f, c1 = 0.f, c2 = 0.f, c3 = 0.f;
        const float* vp = v + (size_t)b * NN * DD + d;
#pragma unroll 4
        for (int j = 0; j < NN; j++) {
            float vv = vp[(size_t)j * DD];
            c0 = fmaf(ar[0][h * 132 + j], vv, c0);
            c1 = fmaf(ar[1][h * 132 + j], vv, c1);
            c2 = fmaf(ar[2][h * 132 + j], vv, c2);
            c3 = fmaf(ar[3][h * 132 + j], vv, c3);
        }
        csmT[0][d] = c0; csmT[1][d] = c1; csmT[2][d] = c2; csmT[3][d] = c3;
    }
    __syncthreads();
    {
        const int c = t;
        float o0 = 0.f, o1 = 0.f, o2 = 0.f, o3 = 0.f;
#pragma unroll 8
        for (int k = 0; k < DD; k++) {
            float w = W_o[(size_t)k * DD + c];
            o0 = fmaf(csmT[0][k], w, o0); o1 = fmaf(csmT[1][k], w, o1);
            o2 = fmaf(csmT[2][k], w, o2); o3 = fmaf(csmT[3][k], w, o3);
        }
        float bo = b_o[c];
        float o[4] = {o0, o1, o2, o3};
#pragma unroll
        for (int il = 0; il < 4; il++) {
            int i = i0 + il;
            if (i < NN) out[((size_t)b * NN + i) * DD + c] = o[il] + bo;
        }
    }
}

extern "C" void kernel_launch(void* const* d_in, const int* in_sizes, int n_in,
                              void* d_out, int out_size, void* d_ws, size_t ws_size,
                              hipStream_t stream) {
    const float* desc   = (const float*)d_in[0];
    const float* nv     = (const float*)d_in[1];
    const float* W_gt   = (const float*)d_in[2];
    const float* b_gt   = (const float*)d_in[3];
    // d_in[4] topo_bias unused: sigmoid(x)>0 always, so adjacency sign = sample_sim sign
    const float* W_q    = (const float*)d_in[5];
    const float* b_q    = (const float*)d_in[6];
    const float* W_k    = (const float*)d_in[7];
    const float* b_k    = (const float*)d_in[8];
    const float* W_v    = (const float*)d_in[9];
    const float* b_v    = (const float*)d_in[10];
    const float* W_e1   = (const float*)d_in[11];
    const float* b_e1   = (const float*)d_in[12];
    const float* ln_g   = (const float*)d_in[13];
    const float* ln_b   = (const float*)d_in[14];
    const float* W_e2   = (const float*)d_in[15];
    const float* b_e2   = (const float*)d_in[16];
    const float* w_attn = (const float*)d_in[17];
    const float* b_attn = (const float*)d_in[18];
    const float* W_o    = (const float*)d_in[19];
    const float* b_o    = (const float*)d_in[20];

    float* ws   = (float*)d_ws;
    float* a    = ws + OFF_A;
    float* bp_t = ws + OFF_BPT;
    float* cp_t = ws + OFF_CPT;
    float* vart = ws + OFF_VART;
    float* v    = ws + OFF_V;
    float* sq   = ws + OFF_SQ;
    float* sk   = ws + OFF_SK;
    float* ma   = ws + OFF_MA;
    float* qa   = ws + OFF_QA;
    float* mb   = ws + OFF_MB;
    float* qb   = ws + OFF_QB;
    float* mc   = ws + OFF_MC;
    float* qc   = ws + OFF_QC;
    float* U    = ws + OFF_U;
    float* ub   = ws + OFF_UB;
    float* G    = ws + OFF_G;
    float* VV   = ws + OFF_VV;

    float* out  = (float*)d_out;
    float* attn = (float*)d_out + (size_t)BB * NN * DD;

    // L1: 128 (desc->a/b proj, M=8) + 136 (qkv, M=8) + 64 (U fold) = 328
    ka3<<<dim3(328), dim3(256), 0, stream>>>(
        desc, nv, W_gt, b_gt, W_e1, b_e1, W_q, b_q, W_k, b_k, W_v, b_v,
        W_e2, b_e2, w_attn,
        a, bp_t, cp_t, vart, v, sq, sk, ma, qa, mb, qb, mc, qc, U, ub);
    // L2: cross-gram G = a@bp^T, mask-gram VV = var@var^T
    kgram<<<dim3(256), dim3(256), 0, stream>>>(a, bp_t, nv, vart, G, VV);
    // L3: scores + softmax (2-i tiles)
    kb3<<<dim3(65, BB), dim3(256), 0, stream>>>(
        a, bp_t, cp_t, ma, qa, mb, qb, mc, qc, G, VV, sq, sk,
        ln_g, ln_b, U, ub, b_attn, attn);
    // L4: ctx + out-proj (4-i tiles)
    kc3<<<dim3(33, BB), dim3(256), 0, stream>>>(attn, v, W_o, b_o, out);
}

// Round 7
// 185.277 us; speedup vs baseline: 1.1421x; 1.1421x over previous
//
#include <hip/hip_runtime.h>
#include <math.h>

#define BB 8
#define SS 128
#define NN 129
#define DD 256
#define HH 8
#define LN_EPS 1e-5f

// ws layout (float offsets)
#define OFF_A    0        // a:     [B][S][D]
#define OFF_BPT  262144   // bp_t:  [B][D][S]  (b_ + b_e1, transposed)
#define OFF_CPT  524288   // cp_t:  [B][D][S]  (a + b_ + b_e1, transposed)
#define OFF_VART 786432   // var_t: [B][D][S]  (nv[:,1:,:] transposed)
#define OFF_V    1048576  // v:     [B][N][D]
#define OFF_SQ   1312768  // sq:    [B][H][N]
#define OFF_SK   1321024  // sk:    [B][H][N]
#define OFF_MA   1329280
#define OFF_QA   1330304
#define OFF_MB   1331328
#define OFF_QB   1332352
#define OFF_MC   1333376
#define OFF_QC   1334400
#define OFF_U    1335424  // U: [D][H]
#define OFF_UB   1337472  // ubias: [H]
#define OFF_G    1337600  // G:  [B][S][S]
#define OFF_VV   1468672  // VV: [B][S][S]

struct SA {  // part A: k1 work (~40.4 KB)
    float dsc[4][DD];
    float drow[4][DD];
    float4 red[8][4][64];
    float part[24][4];
};
struct SB {  // part B: k2 work (~34 KB)
    float rows[2][DD];
    float4 redq[8][2][64];
    float4 redk[8][2][64];
};
union SMA { SA a; SB b; };

// ============ KA (R4 structure, empirically fastest): proj + stats + U-fold =
__global__ __launch_bounds__(512) void ka_all(
    const float* __restrict__ desc, const float* __restrict__ nv,
    const float* __restrict__ W_gt, const float* __restrict__ b_gt,
    const float* __restrict__ W_e1, const float* __restrict__ b_e1,
    const float* __restrict__ W_q, const float* __restrict__ b_q,
    const float* __restrict__ W_k, const float* __restrict__ b_k,
    const float* __restrict__ W_v, const float* __restrict__ b_v,
    const float* __restrict__ W_e2, const float* __restrict__ b_e2,
    const float* __restrict__ w_attn,
    float* __restrict__ a, float* __restrict__ bp_t, float* __restrict__ cp_t,
    float* __restrict__ var_t, float* __restrict__ v,
    float* __restrict__ sq, float* __restrict__ sk,
    float* __restrict__ ma, float* __restrict__ qa, float* __restrict__ mb,
    float* __restrict__ qb, float* __restrict__ mc, float* __restrict__ qc,
    float* __restrict__ U, float* __restrict__ ubias) {
    __shared__ SMA sm;
    const int bx = blockIdx.x, t = threadIdx.x;

    if (bx < 256) {
        // ---------------- part A: d = desc@W_gt; a = d@We1_t; b = d@We1_b ----
        SA& S = sm.a;
        const int b = bx >> 5, s0 = (bx & 31) * 4;
        const int dq = t & 63, kh = t >> 6;
        for (int e = t; e < 4 * DD; e += 512)
            S.dsc[e >> 8][e & 255] = desc[(size_t)(b * SS + s0 + (e >> 8)) * DD + (e & 255)];
        __syncthreads();
        {   // d-gemm, split-k x8
            float4 acc[4];
#pragma unroll
            for (int r = 0; r < 4; r++) acc[r] = make_float4(0.f, 0.f, 0.f, 0.f);
            const int kb = kh * 32;
#pragma unroll 4
            for (int k = kb; k < kb + 32; k++) {
                float4 w = *(const float4*)&W_gt[k * DD + 4 * dq];
#pragma unroll
                for (int r = 0; r < 4; r++) {
                    float x = S.dsc[r][k];
                    acc[r].x = fmaf(x, w.x, acc[r].x); acc[r].y = fmaf(x, w.y, acc[r].y);
                    acc[r].z = fmaf(x, w.z, acc[r].z); acc[r].w = fmaf(x, w.w, acc[r].w);
                }
            }
#pragma unroll
            for (int r = 0; r < 4; r++) S.red[kh][r][dq] = acc[r];
        }
        __syncthreads();
        for (int e = t; e < 4 * DD; e += 512) {
            int r = e >> 8, d2 = e & 255;
            float s = b_gt[d2];
#pragma unroll
            for (int kk = 0; kk < 8; kk++) s += ((const float*)S.red[kk][r])[d2];
            S.drow[r][d2] = s;
        }
        __syncthreads();
        {   // a-gemm
            float4 acc[4];
#pragma unroll
            for (int r = 0; r < 4; r++) acc[r] = make_float4(0.f, 0.f, 0.f, 0.f);
            const int kb = kh * 32;
#pragma unroll 4
            for (int k = kb; k < kb + 32; k++) {
                float4 w = *(const float4*)&W_e1[k * DD + 4 * dq];
#pragma unroll
                for (int r = 0; r < 4; r++) {
                    float x = S.drow[r][k];
                    acc[r].x = fmaf(x, w.x, acc[r].x); acc[r].y = fmaf(x, w.y, acc[r].y);
                    acc[r].z = fmaf(x, w.z, acc[r].z); acc[r].w = fmaf(x, w.w, acc[r].w);
                }
            }
#pragma unroll
            for (int r = 0; r < 4; r++) S.red[kh][r][dq] = acc[r];
        }
        __syncthreads();
        float avf[4];
        if (t < 256) {
            const int d2 = t;
#pragma unroll
            for (int r = 0; r < 4; r++) {
                float s = 0.f;
#pragma unroll
                for (int kk = 0; kk < 8; kk++) s += ((const float*)S.red[kk][r])[d2];
                avf[r] = s;
                a[(size_t)(b * SS + s0 + r) * DD + d2] = s;
            }
        }
        __syncthreads();
        {   // b-gemm
            float4 acc[4];
#pragma unroll
            for (int r = 0; r < 4; r++) acc[r] = make_float4(0.f, 0.f, 0.f, 0.f);
            const int kb = kh * 32;
#pragma unroll 4
            for (int k = kb; k < kb + 32; k++) {
                float4 w = *(const float4*)&W_e1[(DD + k) * DD + 4 * dq];
#pragma unroll
                for (int r = 0; r < 4; r++) {
                    float x = S.drow[r][k];
                    acc[r].x = fmaf(x, w.x, acc[r].x); acc[r].y = fmaf(x, w.y, acc[r].y);
                    acc[r].z = fmaf(x, w.z, acc[r].z); acc[r].w = fmaf(x, w.w, acc[r].w);
                }
            }
#pragma unroll
            for (int r = 0; r < 4; r++) S.red[kh][r][dq] = acc[r];
        }
        __syncthreads();
        if (t < 256) {
            const int d2 = t;
            float bvf[4], cvf[4];
            float be1 = b_e1[d2];
#pragma unroll
            for (int r = 0; r < 4; r++) {
                float s = 0.f;
#pragma unroll
                for (int kk = 0; kk < 8; kk++) s += ((const float*)S.red[kk][r])[d2];
                bvf[r] = s + be1; cvf[r] = avf[r] + bvf[r];
            }
            float4 f4;
            f4.x = bvf[0]; f4.y = bvf[1]; f4.z = bvf[2]; f4.w = bvf[3];
            *(float4*)(bp_t + (size_t)(b * DD + d2) * SS + s0) = f4;
            f4.x = cvf[0]; f4.y = cvf[1]; f4.z = cvf[2]; f4.w = cvf[3];
            *(float4*)(cp_t + (size_t)(b * DD + d2) * SS + s0) = f4;
            float nvv[4];
#pragma unroll
            for (int r = 0; r < 4; r++) nvv[r] = nv[(size_t)(b * NN + 1 + s0 + r) * DD + d2];
            f4.x = nvv[0]; f4.y = nvv[1]; f4.z = nvv[2]; f4.w = nvv[3];
            *(float4*)(var_t + (size_t)(b * DD + d2) * SS + s0) = f4;
            float vals[24];
#pragma unroll
            for (int r = 0; r < 4; r++) {
                vals[r * 6 + 0] = avf[r]; vals[r * 6 + 1] = avf[r] * avf[r];
                vals[r * 6 + 2] = bvf[r]; vals[r * 6 + 3] = bvf[r] * bvf[r];
                vals[r * 6 + 4] = cvf[r]; vals[r * 6 + 5] = cvf[r] * cvf[r];
            }
            int lane = t & 63, wid = t >> 6;
#pragma unroll
            for (int vv = 0; vv < 24; vv++) {
                float x = vals[vv];
                for (int o = 32; o; o >>= 1) x += __shfl_xor(x, o, 64);
                if (lane == 0) S.part[vv][wid] = x;
            }
        }
        __syncthreads();
        if (t < 24) {
            float ssum = (S.part[t][0] + S.part[t][1]) + (S.part[t][2] + S.part[t][3]);
            int st = t % 6;
            int row = b * SS + s0 + t / 6;
            float m = ssum * (1.f / DD);
            float* dstp = (st == 0) ? ma : (st == 1) ? qa : (st == 2) ? mb
                         : (st == 3) ? qb : (st == 4) ? mc : qc;
            dstp[row] = m;
        }
    } else if (bx < 776) {
        // ---------------- part B: qkv on 2 rows, split-k x8 ------------------
        SB& S = sm.b;
        const int idx = bx - 256;
        const int b = idx / 65, n0 = (idx % 65) * 2;
        const int dq = t & 63, kh = t >> 6;
        {
            int r = t >> 8, d2 = t & 255;
            int n = n0 + r; if (n >= NN) n = NN - 1;
            S.rows[r][d2] = nv[(size_t)(b * NN + n) * DD + d2];
        }
        __syncthreads();
        {   // Q,K sweep
            float4 aq[2], ak[2];
#pragma unroll
            for (int r = 0; r < 2; r++) { aq[r] = make_float4(0.f, 0.f, 0.f, 0.f); ak[r] = aq[r]; }
            const int kb = kh * 32;
#pragma unroll 4
            for (int k = kb; k < kb + 32; k++) {
                float4 wq = *(const float4*)&W_q[k * DD + 4 * dq];
                float4 wk = *(const float4*)&W_k[k * DD + 4 * dq];
#pragma unroll
                for (int r = 0; r < 2; r++) {
                    float x = S.rows[r][k];
                    aq[r].x = fmaf(x, wq.x, aq[r].x); aq[r].y = fmaf(x, wq.y, aq[r].y);
                    aq[r].z = fmaf(x, wq.z, aq[r].z); aq[r].w = fmaf(x, wq.w, aq[r].w);
                    ak[r].x = fmaf(x, wk.x, ak[r].x); ak[r].y = fmaf(x, wk.y, ak[r].y);
                    ak[r].z = fmaf(x, wk.z, ak[r].z); ak[r].w = fmaf(x, wk.w, ak[r].w);
                }
            }
#pragma unroll
            for (int r = 0; r < 2; r++) { S.redq[kh][r][dq] = aq[r]; S.redk[kh][r][dq] = ak[r]; }
        }
        __syncthreads();
        {   // finalize q,k -> sq,sk
            const int d2 = t & 255, r = t >> 8;
            const int n = n0 + r;
            float qf = b_q[d2], kf = b_k[d2];
#pragma unroll
            for (int kk = 0; kk < 8; kk++) {
                qf += ((const float*)S.redq[kk][r])[d2];
                kf += ((const float*)S.redk[kk][r])[d2];
            }
            float xq = qf * w_attn[d2 & 31];
            float xk = kf * w_attn[32 + (d2 & 31)];
#pragma unroll
            for (int o = 16; o; o >>= 1) { xq += __shfl_xor(xq, o, 32); xk += __shfl_xor(xk, o, 32); }
            if ((d2 & 31) == 0 && n < NN) {
                sq[(size_t)(b * HH + (d2 >> 5)) * NN + n] = xq;
                sk[(size_t)(b * HH + (d2 >> 5)) * NN + n] = xk;
            }
        }
        __syncthreads();
        {   // V sweep (reuse redq)
            float4 av[2];
#pragma unroll
            for (int r = 0; r < 2; r++) av[r] = make_float4(0.f, 0.f, 0.f, 0.f);
            const int kb = kh * 32;
#pragma unroll 4
            for (int k = kb; k < kb + 32; k++) {
                float4 wv = *(const float4*)&W_v[k * DD + 4 * dq];
#pragma unroll
                for (int r = 0; r < 2; r++) {
                    float x = S.rows[r][k];
                    av[r].x = fmaf(x, wv.x, av[r].x); av[r].y = fmaf(x, wv.y, av[r].y);
                    av[r].z = fmaf(x, wv.z, av[r].z); av[r].w = fmaf(x, wv.w, av[r].w);
                }
            }
#pragma unroll
            for (int r = 0; r < 2; r++) S.redq[kh][r][dq] = av[r];
        }
        __syncthreads();
        {
            const int d2 = t & 255, r = t >> 8;
            const int n = n0 + r;
            if (n < NN) {
                float vf = b_v[d2];
#pragma unroll
                for (int kk = 0; kk < 8; kk++) vf += ((const float*)S.redq[kk][r])[d2];
                v[(size_t)(b * NN + n) * DD + d2] = vf;
            }
        }
    } else {
        // ---------------- part C: fold W_e2/we -> U (coalesced) --------------
        const int ri = bx - 776;  // 0..63, rows ri*4..ri*4+3
        if (t < 256) {
            const int c = t;
            const float wec = w_attn[64 + (c & 31)];
#pragma unroll
            for (int rr = 0; rr < 4; rr++) {
                int r = ri * 4 + rr;
                float x = W_e2[(size_t)r * DD + c] * wec;
#pragma unroll
                for (int o = 16; o; o >>= 1) x += __shfl_xor(x, o, 32);
                if ((c & 31) == 0) U[r * HH + (c >> 5)] = x;
            }
            if (ri == 0) {
                float x = b_e2[c] * wec;
#pragma unroll
                for (int o = 16; o; o >>= 1) x += __shfl_xor(x, o, 32);
                if ((c & 31) == 0) ubias[c >> 5] = x;
            }
        }
    }
}

// ============ KGRAM: G = a@bp^T and VV = var@var^T, 16x64 tiles =============
__global__ __launch_bounds__(256) void kgram(
    const float* __restrict__ a, const float* __restrict__ bp_t,
    const float* __restrict__ nv, const float* __restrict__ var_t,
    float* __restrict__ G, float* __restrict__ VV) {
    const int bx = blockIdx.x, t = threadIdx.x;
    const bool isG = bx < 128;
    const int idx = isG ? bx : bx - 128;
    const int b = idx >> 4, tl = idx & 15;
    const int i0 = (tl >> 1) * 16, j0 = (tl & 1) * 64;
    const float* Asrc = isG ? (a + ((size_t)b * SS + i0) * DD)
                            : (nv + ((size_t)b * NN + 1 + i0) * DD);
    const float* Bt = (isG ? bp_t : var_t) + (size_t)b * DD * SS;
    float* C = (isG ? G : VV) + (size_t)b * SS * SS;
    __shared__ __attribute__((aligned(16))) float Al[16][DD];
    for (int e = t; e < 16 * DD / 4; e += 256) {
        int r = e >> 6, c4 = e & 63;
        *(float4*)&Al[r][c4 * 4] = *(const float4*)&Asrc[(size_t)r * DD + c4 * 4];
    }
    __syncthreads();
    const int dg = t & 3, jl = t >> 2;
    float acc[16] = {0.f, 0.f, 0.f, 0.f, 0.f, 0.f, 0.f, 0.f,
                     0.f, 0.f, 0.f, 0.f, 0.f, 0.f, 0.f, 0.f};
    const float* bp = Bt + (size_t)(dg * 64) * SS + j0 + jl;
#pragma unroll 4
    for (int dd = 0; dd < 64; dd++) {
        float bvv = bp[(size_t)dd * SS];
        int d = dg * 64 + dd;
#pragma unroll
        for (int i = 0; i < 16; i++) acc[i] = fmaf(Al[i][d], bvv, acc[i]);
    }
#pragma unroll
    for (int i = 0; i < 16; i++) {
        acc[i] += __shfl_xor(acc[i], 1);
        acc[i] += __shfl_xor(acc[i], 2);
    }
    if (dg == 0) {
#pragma unroll
        for (int i = 0; i < 16; i++) C[(size_t)(i0 + i) * SS + j0 + jl] = acc[i];
    }
}

// ============ KB4: LN + relu + U-dot + scores + softmax (single B stream) ===
__global__ __launch_bounds__(256) void kb4(
    const float* __restrict__ a, const float* __restrict__ bp_t, const float* __restrict__ cp_t,
    const float* __restrict__ ma, const float* __restrict__ qa,
    const float* __restrict__ mb, const float* __restrict__ qb,
    const float* __restrict__ mc, const float* __restrict__ qc,
    const float* __restrict__ G, const float* __restrict__ VV,
    const float* __restrict__ sq, const float* __restrict__ sk,
    const float* __restrict__ ln_g, const float* __restrict__ ln_b,
    const float* __restrict__ U, const float* __restrict__ ubias,
    const float* __restrict__ b_attn,
    float* __restrict__ attn) {
    const int it = blockIdx.x, b = blockIdx.y;
    const int i0 = it * 2;
    const int t = threadIdx.x;
    const int dg = t >> 6, jl = t & 63;
    __shared__ float Arow[2][DD];
    __shared__ __attribute__((aligned(8))) float2 lnsm[DD];
    __shared__ __attribute__((aligned(16))) float4 Usm[DD][2];
    __shared__ __attribute__((aligned(8))) float rsm[2][SS], nmm[2][SS], mkm[2][SS], pnm[2][SS];
    __shared__ float skm[HH * NN];
    __shared__ float sqb[2][HH], ubm[HH];
    __shared__ float sc[2][HH][NN + 3];
    __shared__ __attribute__((aligned(8))) float red[4][2][HH][SS];

    {
        int ic0 = i0, ic1 = (i0 + 1 < NN) ? i0 + 1 : NN - 1;
        Arow[0][t] = (ic0 >= 1) ? a[((size_t)b * SS + ic0 - 1) * DD + t] : 0.f;
        Arow[1][t] = (ic1 >= 1) ? a[((size_t)b * SS + ic1 - 1) * DD + t] : 0.f;
        float2 g; g.x = ln_g[t]; g.y = ln_b[t]; lnsm[t] = g;
        Usm[t][0] = *(const float4*)&U[t * HH];
        Usm[t][1] = *(const float4*)&U[t * HH + 4];
        for (int e = t; e < HH * NN; e += 256) skm[e] = sk[(size_t)b * HH * NN + e];
        if (t < 16) {
            int il = t >> 3, h = t & 7;
            int i = i0 + il; if (i > NN - 1) i = NN - 1;
            sqb[il][h] = sq[(size_t)b * HH * NN + h * NN + i] + b_attn[0];
        }
        if (t < HH) ubm[t] = ubias[t];
    }
    __syncthreads();
    if (t < SS) {
        const int j = t;
#pragma unroll
        for (int il = 0; il < 2; il++) {
            int i = i0 + il; if (i > NN - 1) i = NN - 1;
            float rs, nm, mk, pen;
            if (i == 0) {
                float mu = mc[b * SS + j], q2 = qc[b * SS + j];
                rs = rsqrtf(q2 - mu * mu + LN_EPS); nm = -mu * rs; mk = 1.f; pen = 0.f;
            } else {
                float cr = G[((size_t)b * SS + i - 1) * SS + j];
                float dv = VV[((size_t)b * SS + i - 1) * SS + j];
                float muA = ma[b * SS + i - 1], qA = qa[b * SS + i - 1];
                float muB = mb[b * SS + j], qB = qb[b * SS + j];
                float mu = muA + muB;
                float var = qA + qB + 2.f * cr * (1.f / DD) - mu * mu;
                rs = rsqrtf(var + LN_EPS); nm = -mu * rs;
                mk = ((i - 1) != j && dv > 0.f) ? 1.f : 0.f;
                pen = (mk == 0.f) ? -1e9f : 0.f;
            }
            rsm[il][j] = rs; nmm[il][j] = nm; mkm[il][j] = mk; pnm[il][j] = pen;
        }
    }
    __syncthreads();
    float acc[2][HH][2];
#pragma unroll
    for (int il = 0; il < 2; il++)
#pragma unroll
        for (int h = 0; h < HH; h++) { acc[il][h][0] = 0.f; acc[il][h][1] = 0.f; }
    {
        const float* Bb = bp_t + ((size_t)b * DD + dg * 64) * SS + 2 * jl;
        float2 r0 = *(const float2*)&rsm[0][2 * jl];
        float2 n0 = *(const float2*)&nmm[0][2 * jl];
        float2 r1 = *(const float2*)&rsm[1][2 * jl];
        float2 n1 = *(const float2*)&nmm[1][2 * jl];
        if (i0 != 0) {
            // rows i0 and i0+1 share the SAME B panel -> one load feeds both
#pragma unroll 4
            for (int dd = 0; dd < 64; dd++) {
                const int d = dg * 64 + dd;
                float2 bv = *(const float2*)(Bb + (size_t)dd * SS);
                float A0 = Arow[0][d], A1 = Arow[1][d];
                float2 gb = lnsm[d];
                float4 u0 = Usm[d][0], u1 = Usm[d][1];
                float y0 = fmaf(A0 + bv.x, r0.x, n0.x); y0 = fmaf(y0, gb.x, gb.y);
                float y1 = fmaf(A0 + bv.y, r0.y, n0.y); y1 = fmaf(y1, gb.x, gb.y);
                float e0 = fmaxf(y0, 0.f), e1 = fmaxf(y1, 0.f);
                float z0 = fmaf(A1 + bv.x, r1.x, n1.x); z0 = fmaf(z0, gb.x, gb.y);
                float z1 = fmaf(A1 + bv.y, r1.y, n1.y); z1 = fmaf(z1, gb.x, gb.y);
                float f0 = fmaxf(z0, 0.f), f1 = fmaxf(z1, 0.f);
                acc[0][0][0] = fmaf(e0, u0.x, acc[0][0][0]); acc[0][0][1] = fmaf(e1, u0.x, acc[0][0][1]);
                acc[0][1][0] = fmaf(e0, u0.y, acc[0][1][0]); acc[0][1][1] = fmaf(e1, u0.y, acc[0][1][1]);
                acc[0][2][0] = fmaf(e0, u0.z, acc[0][2][0]); acc[0][2][1] = fmaf(e1, u0.z, acc[0][2][1]);
                acc[0][3][0] = fmaf(e0, u0.w, acc[0][3][0]); acc[0][3][1] = fmaf(e1, u0.w, acc[0][3][1]);
                acc[0][4][0] = fmaf(e0, u1.x, acc[0][4][0]); acc[0][4][1] = fmaf(e1, u1.x, acc[0][4][1]);
                acc[0][5][0] = fmaf(e0, u1.y, acc[0][5][0]); acc[0][5][1] = fmaf(e1, u1.y, acc[0][5][1]);
                acc[0][6][0] = fmaf(e0, u1.z, acc[0][6][0]); acc[0][6][1] = fmaf(e1, u1.z, acc[0][6][1]);
                acc[0][7][0] = fmaf(e0, u1.w, acc[0][7][0]); acc[0][7][1] = fmaf(e1, u1.w, acc[0][7][1]);
                acc[1][0][0] = fmaf(f0, u0.x, acc[1][0][0]); acc[1][0][1] = fmaf(f1, u0.x, acc[1][0][1]);
                acc[1][1][0] = fmaf(f0, u0.y, acc[1][1][0]); acc[1][1][1] = fmaf(f1, u0.y, acc[1][1][1]);
                acc[1][2][0] = fmaf(f0, u0.z, acc[1][2][0]); acc[1][2][1] = fmaf(f1, u0.z, acc[1][2][1]);
                acc[1][3][0] = fmaf(f0, u0.w, acc[1][3][0]); acc[1][3][1] = fmaf(f1, u0.w, acc[1][3][1]);
                acc[1][4][0] = fmaf(f0, u1.x, acc[1][4][0]); acc[1][4][1] = fmaf(f1, u1.x, acc[1][4][1]);
                acc[1][5][0] = fmaf(f0, u1.y, acc[1][5][0]); acc[1][5][1] = fmaf(f1, u1.y, acc[1][5][1]);
                acc[1][6][0] = fmaf(f0, u1.z, acc[1][6][0]); acc[1][6][1] = fmaf(f1, u1.z, acc[1][6][1]);
                acc[1][7][0] = fmaf(f0, u1.w, acc[1][7][0]); acc[1][7][1] = fmaf(f1, u1.w, acc[1][7][1]);
            }
        } else {
            // i0 == 0: row 0 uses cp_t, row 1 uses bp_t (8 blocks total)
            const float* Bc = cp_t + ((size_t)b * DD + dg * 64) * SS + 2 * jl;
#pragma unroll 4
            for (int dd = 0; dd < 64; dd++) {
                const int d = dg * 64 + dd;
                float2 bA = *(const float2*)(Bc + (size_t)dd * SS);
                float2 bB = *(const float2*)(Bb + (size_t)dd * SS);
                float A0 = Arow[0][d], A1 = Arow[1][d];
                float2 gb = lnsm[d];
                float4 u0 = Usm[d][0], u1 = Usm[d][1];
                float y0 = fmaf(A0 + bA.x, r0.x, n0.x); y0 = fmaf(y0, gb.x, gb.y);
                float y1 = fmaf(A0 + bA.y, r0.y, n0.y); y1 = fmaf(y1, gb.x, gb.y);
                float e0 = fmaxf(y0, 0.f), e1 = fmaxf(y1, 0.f);
                float z0 = fmaf(A1 + bB.x, r1.x, n1.x); z0 = fmaf(z0, gb.x, gb.y);
                float z1 = fmaf(A1 + bB.y, r1.y, n1.y); z1 = fmaf(z1, gb.x, gb.y);
                float f0 = fmaxf(z0, 0.f), f1 = fmaxf(z1, 0.f);
                acc[0][0][0] = fmaf(e0, u0.x, acc[0][0][0]); acc[0][0][1] = fmaf(e1, u0.x, acc[0][0][1]);
                acc[0][1][0] = fmaf(e0, u0.y, acc[0][1][0]); acc[0][1][1] = fmaf(e1, u0.y, acc[0][1][1]);
                acc[0][2][0] = fmaf(e0, u0.z, acc[0][2][0]); acc[0][2][1] = fmaf(e1, u0.z, acc[0][2][1]);
                acc[0][3][0] = fmaf(e0, u0.w, acc[0][3][0]); acc[0][3][1] = fmaf(e1, u0.w, acc[0][3][1]);
                acc[0][4][0] = fmaf(e0, u1.x, acc[0][4][0]); acc[0][4][1] = fmaf(e1, u1.x, acc[0][4][1]);
                acc[0][5][0] = fmaf(e0, u1.y, acc[0][5][0]); acc[0][5][1] = fmaf(e1, u1.y, acc[0][5][1]);
                acc[0][6][0] = fmaf(e0, u1.z, acc[0][6][0]); acc[0][6][1] = fmaf(e1, u1.z, acc[0][6][1]);
                acc[0][7][0] = fmaf(e0, u1.w, acc[0][7][0]); acc[0][7][1] = fmaf(e1, u1.w, acc[0][7][1]);
                acc[1][0][0] = fmaf(f0, u0.x, acc[1][0][0]); acc[1][0][1] = fmaf(f1, u0.x, acc[1][0][1]);
                acc[1][1][0] = fmaf(f0, u0.y, acc[1][1][0]); acc[1][1][1] = fmaf(f1, u0.y, acc[1][1][1]);
                acc[1][2][0] = fmaf(f0, u0.z, acc[1][2][0]); acc[1][2][1] = fmaf(f1, u0.z, acc[1][2][1]);
                acc[1][3][0] = fmaf(f0, u0.w, acc[1][3][0]); acc[1][3][1] = fmaf(f1, u0.w, acc[1][3][1]);
                acc[1][4][0] = fmaf(f0, u1.x, acc[1][4][0]); acc[1][4][1] = fmaf(f1, u1.x, acc[1][4][1]);
                acc[1][5][0] = fmaf(f0, u1.y, acc[1][5][0]); acc[1][5][1] = fmaf(f1, u1.y, acc[1][5][1]);
                acc[1][6][0] = fmaf(f0, u1.z, acc[1][6][0]); acc[1][6][1] = fmaf(f1, u1.z, acc[1][6][1]);
                acc[1][7][0] = fmaf(f0, u1.w, acc[1][7][0]); acc[1][7][1] = fmaf(f1, u1.w, acc[1][7][1]);
            }
        }
    }
#pragma unroll
    for (int il = 0; il < 2; il++)
#pragma unroll
        for (int h = 0; h < HH; h++) {
            float2 w; w.x = acc[il][h][0]; w.y = acc[il][h][1];
            *(float2*)&red[dg][il][h][2 * jl] = w;
        }
    __syncthreads();
    for (int e = t; e < 2 * HH * SS; e += 256) {
        int il = e >> 10, h = (e >> 7) & 7, j = e & 127;
        float s = (red[0][il][h][j] + red[1][il][h][j]) + (red[2][il][h][j] + red[3][il][h][j]);
        sc[il][h][1 + j] = sqb[il][h] + skm[h * NN + 1 + j] + (s + ubm[h]) * mkm[il][j] + pnm[il][j];
    }
    if (t < 16) { int il = t >> 3, h = t & 7; sc[il][h][0] = sqb[il][h] + skm[h * NN] - 1e9f; }
    __syncthreads();
    {
        const int row = t >> 4, l = t & 15;
        const int il = row >> 3, h = row & 7;
        const int i = i0 + il;
        float m = -INFINITY;
        for (int j = l; j < NN; j += 16) m = fmaxf(m, sc[il][h][j]);
#pragma unroll
        for (int o = 8; o; o >>= 1) m = fmaxf(m, __shfl_xor(m, o, 16));
        float s = 0.f;
        for (int j = l; j < NN; j += 16) { float e = __expf(sc[il][h][j] - m); sc[il][h][j] = e; s += e; }
#pragma unroll
        for (int o = 8; o; o >>= 1) s += __shfl_xor(s, o, 16);
        float inv = 1.f / s;
        if (i < NN) {
            float* arow = attn + (((size_t)b * HH + h) * NN + i) * NN;
            for (int j = l; j < NN; j += 16) arow[j] = sc[il][h][j] * inv;
        }
    }
}

// ============ KC4: ctx = attn@v ; out = ctx@W_o + b_o (512 thr, 2-way ILP) ==
__global__ __launch_bounds__(512) void kc4(
    const float* __restrict__ attn, const float* __restrict__ v,
    const float* __restrict__ W_o, const float* __restrict__ b_o,
    float* __restrict__ out) {
    const int b = blockIdx.y, i0 = blockIdx.x * 4;
    const int t = threadIdx.x;
    __shared__ float ar[4][HH * 132];
    __shared__ float red[2][4][DD];
    __shared__ float csm[4][DD];
    for (int e = t; e < 4 * HH * NN; e += 512) {
        int il = e / (HH * NN), rem = e - il * (HH * NN);
        int h = rem / NN, j = rem - h * NN;
        int i = i0 + il; if (i >= NN) i = NN - 1;
        ar[il][h * 132 + j] = attn[(((size_t)b * HH + h) * NN + i) * NN + j];
    }
    __syncthreads();
    {   // ctx: thread = (d, j-half)
        const int d = t & 255, jh = t >> 8;
        const int h = d >> 5;
        float c0 = 0.f, c1 = 0.f, c2 = 0.f, c3 = 0.f;
        const float* vp = v + (size_t)b * NN * DD + d;
        const int j0 = jh * 65, j1 = jh ? NN : 65;
#pragma unroll 4
        for (int j = j0; j < j1; j++) {
            float vv = vp[(size_t)j * DD];
            c0 = fmaf(ar[0][h * 132 + j], vv, c0);
            c1 = fmaf(ar[1][h * 132 + j], vv, c1);
            c2 = fmaf(ar[2][h * 132 + j], vv, c2);
            c3 = fmaf(ar[3][h * 132 + j], vv, c3);
        }
        red[jh][0][d] = c0; red[jh][1][d] = c1; red[jh][2][d] = c2; red[jh][3][d] = c3;
    }
    __syncthreads();
    for (int e = t; e < 4 * DD; e += 512) {
        int il = e >> 8, d = e & 255;
        csm[il][d] = red[0][il][d] + red[1][il][d];
    }
    __syncthreads();
    {   // out: thread = (c, k-half)
        const int c = t & 255, kh = t >> 8;
        float o0 = 0.f, o1 = 0.f, o2 = 0.f, o3 = 0.f;
        const int kb = kh * 128;
#pragma unroll 8
        for (int k = kb; k < kb + 128; k++) {
            float w = W_o[(size_t)k * DD + c];
            o0 = fmaf(csm[0][k], w, o0); o1 = fmaf(csm[1][k], w, o1);
            o2 = fmaf(csm[2][k], w, o2); o3 = fmaf(csm[3][k], w, o3);
        }
        red[kh][0][c] = o0; red[kh][1][c] = o1; red[kh][2][c] = o2; red[kh][3][c] = o3;
    }
    __syncthreads();
    for (int e = t; e < 4 * DD; e += 512) {
        int il = e >> 8, d = e & 255;
        int i = i0 + il;
        if (i < NN)
            out[((size_t)b * NN + i) * DD + d] = red[0][il][d] + red[1][il][d] + b_o[d];
    }
}

extern "C" void kernel_launch(void* const* d_in, const int* in_sizes, int n_in,
                              void* d_out, int out_size, void* d_ws, size_t ws_size,
                              hipStream_t stream) {
    const float* desc   = (const float*)d_in[0];
    const float* nv     = (const float*)d_in[1];
    const float* W_gt   = (const float*)d_in[2];
    const float* b_gt   = (const float*)d_in[3];
    // d_in[4] topo_bias unused: sigmoid(x)>0 always, so adjacency sign = sample_sim sign
    const float* W_q    = (const float*)d_in[5];
    const float* b_q    = (const float*)d_in[6];
    const float* W_k    = (const float*)d_in[7];
    const float* b_k    = (const float*)d_in[8];
    const float* W_v    = (const float*)d_in[9];
    const float* b_v    = (const float*)d_in[10];
    const float* W_e1   = (const float*)d_in[11];
    const float* b_e1   = (const float*)d_in[12];
    const float* ln_g   = (const float*)d_in[13];
    const float* ln_b   = (const float*)d_in[14];
    const float* W_e2   = (const float*)d_in[15];
    const float* b_e2   = (const float*)d_in[16];
    const float* w_attn = (const float*)d_in[17];
    const float* b_attn = (const float*)d_in[18];
    const float* W_o    = (const float*)d_in[19];
    const float* b_o    = (const float*)d_in[20];

    float* ws   = (float*)d_ws;
    float* a    = ws + OFF_A;
    float* bp_t = ws + OFF_BPT;
    float* cp_t = ws + OFF_CPT;
    float* vart = ws + OFF_VART;
    float* v    = ws + OFF_V;
    float* sq   = ws + OFF_SQ;
    float* sk   = ws + OFF_SK;
    float* ma   = ws + OFF_MA;
    float* qa   = ws + OFF_QA;
    float* mb   = ws + OFF_MB;
    float* qb   = ws + OFF_QB;
    float* mc   = ws + OFF_MC;
    float* qc   = ws + OFF_QC;
    float* U    = ws + OFF_U;
    float* ub   = ws + OFF_UB;
    float* G    = ws + OFF_G;
    float* VV   = ws + OFF_VV;

    float* out  = (float*)d_out;
    float* attn = (float*)d_out + (size_t)BB * NN * DD;

    // L1 (R4 structure): 256 projA + 520 qkv + 64 U-fold = 840 blocks
    ka_all<<<dim3(840), dim3(512), 0, stream>>>(
        desc, nv, W_gt, b_gt, W_e1, b_e1, W_q, b_q, W_k, b_k, W_v, b_v,
        W_e2, b_e2, w_attn,
        a, bp_t, cp_t, vart, v, sq, sk, ma, qa, mb, qb, mc, qc, U, ub);
    // L2: cross-gram + mask-gram
    kgram<<<dim3(256), dim3(256), 0, stream>>>(a, bp_t, nv, vart, G, VV);
    // L3: scores + softmax
    kb4<<<dim3(65, BB), dim3(256), 0, stream>>>(
        a, bp_t, cp_t, ma, qa, mb, qb, mc, qc, G, VV, sq, sk,
        ln_g, ln_b, U, ub, b_attn, attn);
    // L4: ctx + out-proj
    kc4<<<dim3(33, BB), dim3(512), 0, stream>>>(attn, v, W_o, b_o, out);
}